// Round 16
// baseline (990.151 us; speedup 1.0000x reference)
//
#include <hip/hip_runtime.h>

#define TT 512
#define HH 256

typedef _Float16 half2t __attribute__((ext_vector_type(2)));

// fp16-pair dot with fp32 accumulate (v_dot2_f32_f16 when available).
__device__ __forceinline__ float dot2acc(unsigned w, unsigned h, float acc) {
#if __has_builtin(__builtin_amdgcn_fdot2)
    return __builtin_amdgcn_fdot2(__builtin_bit_cast(half2t, w),
                                  __builtin_bit_cast(half2t, h), acc, false);
#else
    union U { unsigned u; _Float16 f[2]; };
    U uw, uh; uw.u = w; uh.u = h;
    acc = __builtin_fmaf((float)uw.f[0], (float)uh.f[0], acc);
    acc = __builtin_fmaf((float)uw.f[1], (float)uh.f[1], acc);
    return acc;
#endif
}

__device__ __forceinline__ unsigned packh2(float a, float b) {
    union U { _Float16 f[2]; unsigned u; } r;
    r.f[0] = (_Float16)a; r.f[1] = (_Float16)b;   // RNE conversion
    return r.u;
}

// C=1: one 512-thread wg per batch (128 wgs, plain launch), NO cross-CU
// exchange. Thread j owns gate-rows j (i/f) and j+512 (g/o):
// K[0..191] as 192 packed-fp16 VGPR words, K[192..255] in 128KB LDS.
// h as 128 fp16-pairs in LDS (broadcast b128 reads, conflict-free).
// Each thread's acc = complete row sum -> no reduction; 2 barriers/step.
//
// R16 change (single variable): amdgpu_waves_per_eu(2,2). The 136KB LDS
// already forces 1 wg/CU = 8 waves = 2 waves/EU; requesting exactly that
// raises the VGPR budget 128 -> 256, so the 192 weight words stop spilling
// to scratch (R15: VGPR_Count=128, ~0.9us/step scratch reload + 35ms
// first-touch outlier).
__global__ __launch_bounds__(512)
__attribute__((amdgpu_waves_per_eu(2, 2)))
void lstm_single(
    const float* __restrict__ x,      // [B,T]
    const float* __restrict__ W_ih,   // [1024]
    const float* __restrict__ W_hh,   // [1024,256]
    const float* __restrict__ b_ih,   // [1024]
    const float* __restrict__ b_hh,   // [1024]
    const float* __restrict__ W1,     // [128,256]
    const float* __restrict__ b1,     // [128]
    const float* __restrict__ W2,     // [128]
    const float* __restrict__ b2,     // [1]
    float* __restrict__ out)          // [B]
{
    const int b = blockIdx.x;
    const int j = threadIdx.x;        // 0..511

    __shared__ unsigned wl[16][512][4];   // 128 KB: LDS weight tail
    __shared__ unsigned h_lds[128];       // 512 B: h as fp16 pairs
    __shared__ float    h32[HH];          // 1 KB: h fp32 (epilogue)
    __shared__ float    gates[1024];      // 4 KB
    __shared__ float    x_lds[TT];        // 2 KB
    __shared__ float    red[128];         // 512 B

    const int rA = j;                 // gate-rows: rA in {i,f}, rB in {g,o}
    const int rB = j + 512;
    const float* pA = W_hh + (size_t)rA * HH;
    const float* pB = W_hh + (size_t)rB * HH;

    // ---- stage weights: K[0..191] -> 192 packed VGPRs, K[192..255] -> LDS
    unsigned wvA[96], wvB[96];
    #pragma unroll
    for (int k = 0; k < 96; ++k) {
        wvA[k] = packh2(pA[2 * k], pA[2 * k + 1]);
        wvB[k] = packh2(pB[2 * k], pB[2 * k + 1]);
    }
    #pragma unroll
    for (int k = 0; k < 96; ++k) {
        asm volatile("" : "+v"(wvA[k]));
        asm volatile("" : "+v"(wvB[k]));
    }
    #pragma unroll
    for (int blk = 0; blk < 8; ++blk) {
        #pragma unroll
        for (int u = 0; u < 4; ++u) {
            const int k = 192 + 2 * (blk * 4 + u);   // fp32 element index
            wl[blk][j][u]     = packh2(pA[k], pA[k + 1]);
            wl[8 + blk][j][u] = packh2(pB[k], pB[k + 1]);
        }
    }

    // per-row input weight + bias
    const float wihA  = W_ih[rA];
    const float biasA = b_ih[rA] + b_hh[rA];
    const float wihB  = W_ih[rB];
    const float biasB = b_ih[rB] + b_hh[rB];

    // stage x; init h
    x_lds[j] = x[(size_t)b * TT + j];
    if (j < 128) h_lds[j] = 0u;
    if (j < 256) h32[j] = 0.0f;
    float c = 0.0f;                   // cell state (threads 0..255, elem j)
    __syncthreads();

    for (int t = 0; t < TT; ++t) {
        // ---- dot: both rows vs full h (fp16 pairs), fp32 accumulate
        float accA = 0.f, accB = 0.f;
        const uint4* hq4 = reinterpret_cast<const uint4*>(h_lds);
        #pragma unroll
        for (int i = 0; i < 24; ++i) {                 // words 0..95 (VGPR weights)
            uint4 hq = hq4[i];                         // broadcast ds_read_b128
            accA = dot2acc(wvA[4*i+0], hq.x, accA); accB = dot2acc(wvB[4*i+0], hq.x, accB);
            accA = dot2acc(wvA[4*i+1], hq.y, accA); accB = dot2acc(wvB[4*i+1], hq.y, accB);
            accA = dot2acc(wvA[4*i+2], hq.z, accA); accB = dot2acc(wvB[4*i+2], hq.z, accB);
            accA = dot2acc(wvA[4*i+3], hq.w, accA); accB = dot2acc(wvB[4*i+3], hq.w, accB);
        }
        #pragma unroll
        for (int blk = 0; blk < 8; ++blk) {            // words 96..127 (LDS weights)
            uint4 hq  = hq4[24 + blk];
            uint4 wqA = *reinterpret_cast<const uint4*>(&wl[blk][j][0]);
            uint4 wqB = *reinterpret_cast<const uint4*>(&wl[8 + blk][j][0]);
            accA = dot2acc(wqA.x, hq.x, accA); accB = dot2acc(wqB.x, hq.x, accB);
            accA = dot2acc(wqA.y, hq.y, accA); accB = dot2acc(wqB.y, hq.y, accB);
            accA = dot2acc(wqA.z, hq.z, accA); accB = dot2acc(wqB.z, hq.z, accB);
            accA = dot2acc(wqA.w, hq.w, accA); accB = dot2acc(wqB.w, hq.w, accB);
        }
        const float xv = x_lds[t];
        gates[j]       = accA + __builtin_fmaf(xv, wihA, biasA);
        gates[j + 512] = accB + __builtin_fmaf(xv, wihB, biasB);
        __syncthreads();

        // ---- cell update: threads 0..255 (element j)
        if (j < 256) {
            float gi = gates[j];
            float gf = gates[256 + j];
            float gg = gates[512 + j];
            float go = gates[768 + j];
            gi = __builtin_amdgcn_rcpf(1.f + __expf(-gi));
            gf = __builtin_amdgcn_rcpf(1.f + __expf(-gf));
            go = __builtin_amdgcn_rcpf(1.f + __expf(-go));
            gg = 2.f * __builtin_amdgcn_rcpf(1.f + __expf(-2.f * gg)) - 1.f;
            c = __builtin_fmaf(gf, c, gi * gg);
            float th = 2.f * __builtin_amdgcn_rcpf(1.f + __expf(-2.f * c)) - 1.f;
            float hn = go * th;
            h32[j] = hn;
            reinterpret_cast<unsigned short*>(h_lds)[j] =
                __builtin_bit_cast(unsigned short, (_Float16)hn);
        }
        __syncthreads();
    }

    // ---- epilogue MLP: y = relu(h @ W1.T + b1) @ W2.T + b2
    if (j < 128) {
        const float4* w1p = reinterpret_cast<const float4*>(W1 + (size_t)j * HH);
        const float4* hp  = reinterpret_cast<const float4*>(h32);
        float s0 = 0.f, s1 = 0.f, s2 = 0.f, s3 = 0.f;
        #pragma unroll
        for (int k = 0; k < 64; ++k) {
            float4 wv = w1p[k], hv = hp[k];
            s0 = __builtin_fmaf(wv.x, hv.x, s0);
            s1 = __builtin_fmaf(wv.y, hv.y, s1);
            s2 = __builtin_fmaf(wv.z, hv.z, s2);
            s3 = __builtin_fmaf(wv.w, hv.w, s3);
        }
        float rv = fmaxf((s0 + s1) + (s2 + s3) + b1[j], 0.f);
        red[j] = rv * W2[j];
    }
    __syncthreads();
    if (j == 0) {
        float y = b2[0];
        #pragma unroll 4
        for (int k = 0; k < 128; ++k) y += red[k];
        out[b] = y;
    }
}

extern "C" void kernel_launch(void* const* d_in, const int* in_sizes, int n_in,
                              void* d_out, int out_size, void* d_ws, size_t ws_size,
                              hipStream_t stream) {
    const float* x    = (const float*)d_in[0];
    const float* W_ih = (const float*)d_in[1];
    const float* W_hh = (const float*)d_in[2];
    const float* b_ih = (const float*)d_in[3];
    const float* b_hh = (const float*)d_in[4];
    const float* W1   = (const float*)d_in[5];
    const float* b1   = (const float*)d_in[6];
    const float* W2   = (const float*)d_in[7];
    const float* b2   = (const float*)d_in[8];
    float* out = (float*)d_out;

    lstm_single<<<128, 512, 0, stream>>>(x, W_ih, W_hh, b_ih, b_hh,
                                         W1, b1, W2, b2, out);
}